// Round 20
// baseline (72.149 us; speedup 1.0000x reference)
//
#include <hip/hip_runtime.h>
#include <hip/hip_bf16.h>
#include <math.h>

// Problem constants
#define QN 2048
#define CN 10
#define SN 16
#define DN 256
#define H1N 256
#define H2N 128
#define H3N 64
#define H4N 10
#define NROW 160        // C*S support rows
#define PRE_AB_BLOCKS (QN / 4 + NROW / 4)   // 552

// Padded LDS row strides (bytes); stride/4 ≡ 4 (mod 32)
#define SH 272   // h1 half-tile / h2 row: 128 bf16 = 256B + 16 pad
#define S3 144   // h3: 64 bf16 = 128B + 16 pad

typedef __attribute__((ext_vector_type(8)))  short  bf16x8s;  // 8 bf16 = 4 VGPR
typedef __attribute__((ext_vector_type(4)))  float  f32x4;
typedef __attribute__((ext_vector_type(16))) float  f32x16;

static __device__ __forceinline__ unsigned short f2bf(float f) {
  __hip_bfloat16 h = __float2bfloat16(f);
  return __builtin_bit_cast(unsigned short, h);
}

static __device__ __forceinline__ float fast_tanh(float x) {
  const float xc = fminf(fmaxf(x, -15.f), 15.f);
  const float e = __expf(2.f * xc);
  return (e - 1.f) / (e + 1.f);
}

// ---------------------------------------------------------------------------
// Kernel 1 (merged): layer-1 factorization + weight fragment packing.
// ---------------------------------------------------------------------------
__global__ __launch_bounds__(256) void k_pre(
    const float* __restrict__ queries, const float* __restrict__ supports,
    const float* __restrict__ W1, const float* __restrict__ b1,
    const float* __restrict__ W2, const float* __restrict__ W3,
    const float* __restrict__ W4,
    float* __restrict__ A, float* __restrict__ Bm,
    ushort* __restrict__ fb2, ushort* __restrict__ fb3, ushort* __restrict__ fb4) {
  __shared__ float xs[4][DN];
  const int bid = blockIdx.x;
  const int t = threadIdx.x;

  if (bid < PRE_AB_BLOCKS) {
    const bool isA = bid < (QN / 4);
    const int row0 = isA ? bid * 4 : (bid - QN / 4) * 4;
    const float* src = isA ? (queries + (size_t)row0 * DN) : (supports + (size_t)row0 * DN);
    for (int r = 0; r < 4; ++r) xs[r][t] = src[r * DN + t];
    __syncthreads();
    const float* w = W1 + (isA ? 0 : DN * H1N) + t;  // column t
    float acc0 = 0.f, acc1 = 0.f, acc2 = 0.f, acc3 = 0.f;
#pragma unroll 8
    for (int d = 0; d < DN; ++d) {
      const float wv = w[(size_t)d * H1N];
      acc0 += xs[0][d] * wv;
      acc1 += xs[1][d] * wv;
      acc2 += xs[2][d] * wv;
      acc3 += xs[3][d] * wv;
    }
    const float bias = isA ? b1[t] : 0.f;
    float* dst = isA ? A : Bm;
    dst[(row0 + 0) * H1N + t] = acc0 + bias;
    dst[(row0 + 1) * H1N + t] = acc1 + bias;
    dst[(row0 + 2) * H1N + t] = acc2 + bias;
    dst[(row0 + 3) * H1N + t] = acc3 + bias;
    return;
  }

  // ---- weight packing ----
  const int f = (bid - PRE_AB_BLOCKS) * 4 + (t >> 6);
  const int l = t & 63;
  if (f >= 82) return;
  ushort o[8];
  if (f < 64) {
    const int ct = f >> 4, ks = f & 15;
    const int col = ct * 32 + (l & 31);
    const int k0 = ks * 16 + (l >> 5) * 8;
#pragma unroll
    for (int j = 0; j < 8; ++j) o[j] = f2bf(W2[(size_t)(k0 + j) * H2N + col]);
#pragma unroll
    for (int j = 0; j < 8; ++j) fb2[(size_t)f * 512 + l * 8 + j] = o[j];
  } else if (f < 80) {
    const int g = f - 64;
    const int ct = g >> 3, ks = g & 7;
    const int col = ct * 32 + (l & 31);
    const int k0 = ks * 16 + (l >> 5) * 8;
#pragma unroll
    for (int j = 0; j < 8; ++j) o[j] = f2bf(W3[(size_t)(k0 + j) * H3N + col]);
#pragma unroll
    for (int j = 0; j < 8; ++j) fb3[(size_t)g * 512 + l * 8 + j] = o[j];
  } else {
    const int ks = f - 80;
    const int col = l & 15;
    const int k0 = ks * 32 + (l >> 4) * 8;
#pragma unroll
    for (int j = 0; j < 8; ++j)
      o[j] = (col < H4N) ? f2bf(W4[(size_t)(k0 + j) * H4N + col]) : (ushort)0;
#pragma unroll
    for (int j = 0; j < 8; ++j) fb4[(size_t)ks * 512 + l * 8 + j] = o[j];
  }
}

// ---------------------------------------------------------------------------
// Kernel 2: MFMA layers 2-4 + tanh + mean + item-sum.
// Round-20: champion (r15) + DOUBLE-BUFFERED k-halves. stage-half1 is fused
// INTO the G2a MFMA loop (one stage-iter per k-step, writing bufB while
// reading bufA) -> barriers 6 -> 4 and stage1 hides under G2a's MFMAs.
// This removes serial dependencies (structural) rather than reordering
// instructions (r11/r18 failures) or forcing occupancy (r6/r12/r13 spills).
// Aliasing: h2 writes bufA only after bar(2) (all G2a bufA-reads done);
// concurrent G2b reads are bufB (disjoint). LDS 44.0 KB -> 3 blocks/CU
// (= champion's MEASURED residency). Point-of-use loads keep live set small.
// ---------------------------------------------------------------------------
__global__ __launch_bounds__(256) void k_main(
    const float* __restrict__ A, const float* __restrict__ Bm,
    const ushort* __restrict__ fb2, const ushort* __restrict__ fb3,
    const ushort* __restrict__ fb4,
    const float* __restrict__ b2, const float* __restrict__ b3,
    const float* __restrict__ b4, float* __restrict__ out) {
  __shared__ __align__(16) unsigned char smem[2 * 64 * SH + 64 * S3];  // 44032 B
  unsigned char* bufA = smem;                 // h1 half0, later h2 (stride SH)
  unsigned char* bufB = smem + 64 * SH;       // h1 half1 (stride SH)
  unsigned char* h3s  = smem + 2 * 64 * SH;   // [64][64 bf16] stride S3

  const int t = threadIdx.x;
  const int wid = t >> 6;        // 0..3
  const int l = t & 63;
  const int l31 = l & 31;
  const int l15 = l & 15;
  const int lh = l >> 5;         // 0..1
  const int wr = wid >> 1;       // 0..1 (32-row half)
  const int wc = wid & 1;        // 0..1 (col half)

  const bf16x8s* fb2v = (const bf16x8s*)fb2;
  const bf16x8s* fb3v = (const bf16x8s*)fb3;
  const bf16x8s* fb4v = (const bf16x8s*)fb4;

  const int rg0 = blockIdx.x * 64;
  const int q0 = rg0 / NROW;
  const int b0 = rg0 - q0 * NROW;
  const int ct0 = wc * 2;
  const int kh = lh * 16;   // byte offset of lane's 8-bf16 k-slice

  f32x16 acc2a, acc2b;
#pragma unroll
  for (int i = 0; i < 16; ++i) { acc2a[i] = 0.f; acc2b[i] = 0.f; }

  // ---- stage half 0 -> bufA
#pragma unroll
  for (int it = 0; it < 8; ++it) {
    const int row = wid * 16 + it * 2 + lh;
    int bb = b0 + row;
    int qq = q0;
    if (bb >= NROW) { bb -= NROW; qq += 1; }
    const int col = l31 * 4;
    const float4 av = *(const float4*)(A + (size_t)qq * DN + col);
    const float4 bv = *(const float4*)(Bm + (size_t)bb * DN + col);
    ushort4 o;
    o.x = f2bf(fmaxf(av.x + bv.x, 0.f));
    o.y = f2bf(fmaxf(av.y + bv.y, 0.f));
    o.z = f2bf(fmaxf(av.z + bv.z, 0.f));
    o.w = f2bf(fmaxf(av.w + bv.w, 0.f));
    *(ushort4*)(bufA + row * SH + l31 * 8) = o;
  }
  __syncthreads();   // bar(1): bufA ready

  // ---- G2a (ks 0..7 from bufA) FUSED with stage half 1 -> bufB
  {
    const unsigned char* abase = bufA + (32 * wr + l31) * SH;
#pragma unroll
    for (int ks = 0; ks < 8; ++ks) {
      const bf16x8s a = *(const bf16x8s*)(abase + ks * 32 + kh);
      const bf16x8s bA = fb2v[((ct0 + 0) * 16 + ks) * 64 + l];
      const bf16x8s bB = fb2v[((ct0 + 1) * 16 + ks) * 64 + l];
      acc2a = __builtin_amdgcn_mfma_f32_32x32x16_bf16(a, bA, acc2a, 0, 0, 0);
      acc2b = __builtin_amdgcn_mfma_f32_32x32x16_bf16(a, bB, acc2b, 0, 0, 0);
      // stage iter ks of half 1 (independent of the MFMAs -> overlaps)
      const int row = wid * 16 + ks * 2 + lh;
      int bb = b0 + row;
      int qq = q0;
      if (bb >= NROW) { bb -= NROW; qq += 1; }
      const int col = 128 + l31 * 4;
      const float4 av = *(const float4*)(A + (size_t)qq * DN + col);
      const float4 bv = *(const float4*)(Bm + (size_t)bb * DN + col);
      ushort4 o;
      o.x = f2bf(fmaxf(av.x + bv.x, 0.f));
      o.y = f2bf(fmaxf(av.y + bv.y, 0.f));
      o.z = f2bf(fmaxf(av.z + bv.z, 0.f));
      o.w = f2bf(fmaxf(av.w + bv.w, 0.f));
      *(ushort4*)(bufB + row * SH + l31 * 8) = o;
    }
  }
  __syncthreads();   // bar(2): bufB ready; all bufA reads (G2a) done

  // ---- G2b (ks 8..15 from bufB)
  {
    const unsigned char* abase = bufB + (32 * wr + l31) * SH;
#pragma unroll
    for (int ks = 0; ks < 8; ++ks) {
      const bf16x8s a = *(const bf16x8s*)(abase + ks * 32 + kh);
      const bf16x8s bA = fb2v[((ct0 + 0) * 16 + 8 + ks) * 64 + l];
      const bf16x8s bB = fb2v[((ct0 + 1) * 16 + 8 + ks) * 64 + l];
      acc2a = __builtin_amdgcn_mfma_f32_32x32x16_bf16(a, bA, acc2a, 0, 0, 0);
      acc2b = __builtin_amdgcn_mfma_f32_32x32x16_bf16(a, bB, acc2b, 0, 0, 0);
    }
  }

  // ---- h2 = relu(acc2 + b2) -> bufA (safe: bufA reads done at bar(2);
  //      other waves still in G2b read bufB, disjoint)
  {
    const int c0g2 = 64 * wc + l31;
    const float bias2a = b2[c0g2];
    const float bias2b = b2[c0g2 + 32];
#pragma unroll
    for (int reg = 0; reg < 16; ++reg) {
      const int row = 32 * wr + (reg & 3) + 8 * (reg >> 2) + 4 * lh;
      *(ushort*)(bufA + row * SH + c0g2 * 2) =
          f2bf(fmaxf(acc2a[reg] + bias2a, 0.f));
      *(ushort*)(bufA + row * SH + c0g2 * 2 + 64) =
          f2bf(fmaxf(acc2b[reg] + bias2b, 0.f));
    }
  }
  __syncthreads();   // bar(3): h2 (bufA) ready

  // ---- GEMM3: h3 = relu(h2 @ W3 + b3); fb3 streamed (L1-resident, 8 KB)
  f32x16 acc3;
#pragma unroll
  for (int i = 0; i < 16; ++i) acc3[i] = 0.f;
  {
    const unsigned char* abase = bufA + (32 * wr + l31) * SH;
#pragma unroll
    for (int ks = 0; ks < 8; ++ks) {
      const bf16x8s a = *(const bf16x8s*)(abase + ks * 32 + kh);
      const bf16x8s bb3 = fb3v[(wc * 8 + ks) * 64 + l];
      acc3 = __builtin_amdgcn_mfma_f32_32x32x16_bf16(a, bb3, acc3, 0, 0, 0);
    }
  }
  // h3s region is disjoint from bufA -> no barrier needed before writes
  {
    const float bias3 = b3[32 * wc + l31];   // loaded at use
#pragma unroll
    for (int reg = 0; reg < 16; ++reg) {
      const int row = 32 * wr + (reg & 3) + 8 * (reg >> 2) + 4 * lh;
      *(ushort*)(h3s + row * S3 + (32 * wc + l31) * 2) =
          f2bf(fmaxf(acc3[reg] + bias3, 0.f));
    }
  }
  __syncthreads();   // bar(4): h3 ready

  // ---- GEMM4 (16x16x32): wave wid owns rows 16*wid..+16 (one (q,c) group)
  f32x4 acc4;
#pragma unroll
  for (int i = 0; i < 4; ++i) acc4[i] = 0.f;
  {
    const unsigned char* abase = h3s + (16 * wid + l15) * S3;
#pragma unroll
    for (int ks = 0; ks < 2; ++ks) {
      const bf16x8s a = *(const bf16x8s*)(abase + (l >> 4) * 16 + ks * 64);
      const bf16x8s b4f = fb4v[ks * 64 + l];
      acc4 = __builtin_amdgcn_mfma_f32_16x16x32_bf16(a, b4f, acc4, 0, 0, 0);
    }
  }

  // ---- epilogue: tanh, sum 10 cols, mean, sum 16 rows -> score
  {
    const float b4v = (l15 < H4N) ? b4[l15] : 0.f;
    float part = 0.f;
#pragma unroll
    for (int r = 0; r < 4; ++r) {
      const float v = fast_tanh(acc4[r] + b4v);
      part += (l15 < H4N) ? v : 0.f;
    }
    part += __shfl_xor(part, 1);
    part += __shfl_xor(part, 2);
    part += __shfl_xor(part, 4);
    part += __shfl_xor(part, 8);
    part += __shfl_xor(part, 16);
    part += __shfl_xor(part, 32);
    if (l == 0) out[(size_t)blockIdx.x * 4 + wid] = part * 0.1f;
  }
}

// ---------------------------------------------------------------------------
extern "C" void kernel_launch(void* const* d_in, const int* in_sizes, int n_in,
                              void* d_out, int out_size, void* d_ws, size_t ws_size,
                              hipStream_t stream) {
  const float* queries  = (const float*)d_in[0];
  const float* supports = (const float*)d_in[1];
  const float* W1 = (const float*)d_in[2];
  const float* b1 = (const float*)d_in[3];
  const float* W2 = (const float*)d_in[4];
  const float* b2 = (const float*)d_in[5];
  const float* W3 = (const float*)d_in[6];
  const float* b3 = (const float*)d_in[7];
  const float* W4 = (const float*)d_in[8];
  const float* b4 = (const float*)d_in[9];
  float* out = (float*)d_out;

  // workspace layout (fp32 A/Bm, then bf16 fragment buffers) ~2.35 MB
  float* A  = (float*)d_ws;                       // [2048][256]
  float* Bm = A + (size_t)QN * H1N;               // [160][256]
  ushort* fb2 = (ushort*)(Bm + (size_t)NROW * H1N);  // 64*512
  ushort* fb3 = fb2 + 64 * 512;                      // 16*512
  ushort* fb4 = fb3 + 16 * 512;                      // 2*512

  hipLaunchKernelGGL(k_pre, dim3(PRE_AB_BLOCKS + 21), dim3(256), 0, stream,
                     queries, supports, W1, b1, W2, W3, W4, A, Bm, fb2, fb3, fb4);
  hipLaunchKernelGGL(k_main, dim3((QN * CN * SN) / 64), dim3(256), 0, stream,
                     A, Bm, fb2, fb3, fb4, b2, b3, b4, out);
}

// Round 21
// 68.311 us; speedup vs baseline: 1.0562x; 1.0562x over previous
//
#include <hip/hip_runtime.h>
#include <hip/hip_bf16.h>
#include <math.h>

// Problem constants
#define QN 2048
#define CN 10
#define SN 16
#define DN 256
#define H1N 256
#define H2N 128
#define H3N 64
#define H4N 10
#define NROW 160        // C*S support rows
#define PRE_AB_BLOCKS (QN / 4 + NROW / 4)   // 552

// Padded LDS row strides (bytes); stride/4 ≡ 4 (mod 32)
#define SH 272   // h1 half-tile / h2 row: 128 bf16 = 256B + 16 pad
#define S3 144   // h3: 64 bf16 = 128B + 16 pad

typedef __attribute__((ext_vector_type(8)))  short  bf16x8s;  // 8 bf16 = 4 VGPR
typedef __attribute__((ext_vector_type(4)))  float  f32x4;
typedef __attribute__((ext_vector_type(16))) float  f32x16;

static __device__ __forceinline__ unsigned short f2bf(float f) {
  __hip_bfloat16 h = __float2bfloat16(f);
  return __builtin_bit_cast(unsigned short, h);
}

static __device__ __forceinline__ float fast_tanh(float x) {
  const float xc = fminf(fmaxf(x, -15.f), 15.f);
  const float e = __expf(2.f * xc);
  return (e - 1.f) / (e + 1.f);
}

// ---------------------------------------------------------------------------
// Kernel 1 (merged): layer-1 factorization + weight fragment packing.
// ---------------------------------------------------------------------------
__global__ __launch_bounds__(256) void k_pre(
    const float* __restrict__ queries, const float* __restrict__ supports,
    const float* __restrict__ W1, const float* __restrict__ b1,
    const float* __restrict__ W2, const float* __restrict__ W3,
    const float* __restrict__ W4,
    float* __restrict__ A, float* __restrict__ Bm,
    ushort* __restrict__ fb2, ushort* __restrict__ fb3, ushort* __restrict__ fb4) {
  __shared__ float xs[4][DN];
  const int bid = blockIdx.x;
  const int t = threadIdx.x;

  if (bid < PRE_AB_BLOCKS) {
    const bool isA = bid < (QN / 4);
    const int row0 = isA ? bid * 4 : (bid - QN / 4) * 4;
    const float* src = isA ? (queries + (size_t)row0 * DN) : (supports + (size_t)row0 * DN);
    for (int r = 0; r < 4; ++r) xs[r][t] = src[r * DN + t];
    __syncthreads();
    const float* w = W1 + (isA ? 0 : DN * H1N) + t;  // column t
    float acc0 = 0.f, acc1 = 0.f, acc2 = 0.f, acc3 = 0.f;
#pragma unroll 8
    for (int d = 0; d < DN; ++d) {
      const float wv = w[(size_t)d * H1N];
      acc0 += xs[0][d] * wv;
      acc1 += xs[1][d] * wv;
      acc2 += xs[2][d] * wv;
      acc3 += xs[3][d] * wv;
    }
    const float bias = isA ? b1[t] : 0.f;
    float* dst = isA ? A : Bm;
    dst[(row0 + 0) * H1N + t] = acc0 + bias;
    dst[(row0 + 1) * H1N + t] = acc1 + bias;
    dst[(row0 + 2) * H1N + t] = acc2 + bias;
    dst[(row0 + 3) * H1N + t] = acc3 + bias;
    return;
  }

  // ---- weight packing ----
  const int f = (bid - PRE_AB_BLOCKS) * 4 + (t >> 6);
  const int l = t & 63;
  if (f >= 82) return;
  ushort o[8];
  if (f < 64) {
    const int ct = f >> 4, ks = f & 15;
    const int col = ct * 32 + (l & 31);
    const int k0 = ks * 16 + (l >> 5) * 8;
#pragma unroll
    for (int j = 0; j < 8; ++j) o[j] = f2bf(W2[(size_t)(k0 + j) * H2N + col]);
#pragma unroll
    for (int j = 0; j < 8; ++j) fb2[(size_t)f * 512 + l * 8 + j] = o[j];
  } else if (f < 80) {
    const int g = f - 64;
    const int ct = g >> 3, ks = g & 7;
    const int col = ct * 32 + (l & 31);
    const int k0 = ks * 16 + (l >> 5) * 8;
#pragma unroll
    for (int j = 0; j < 8; ++j) o[j] = f2bf(W3[(size_t)(k0 + j) * H3N + col]);
#pragma unroll
    for (int j = 0; j < 8; ++j) fb3[(size_t)g * 512 + l * 8 + j] = o[j];
  } else {
    const int ks = f - 80;
    const int col = l & 15;
    const int k0 = ks * 32 + (l >> 4) * 8;
#pragma unroll
    for (int j = 0; j < 8; ++j)
      o[j] = (col < H4N) ? f2bf(W4[(size_t)(k0 + j) * H4N + col]) : (ushort)0;
#pragma unroll
    for (int j = 0; j < 8; ++j) fb4[(size_t)ks * 512 + l * 8 + j] = o[j];
  }
}

// ---------------------------------------------------------------------------
// Kernel 2: MFMA layers 2-4 + tanh + mean + item-sum.  (FINAL — r15 champion)
// 64-row blocks, 4 waves (wr=wid>>1 row half, wc=wid&1 col half); k-split
// h1 staging (two 128-col halves through one buffer); h2 aliases h1 buffer;
// point-of-use scalar/B4 loads keep the live set at exactly 64 VGPR (the
// 8-waves/SIMD cliff). NO min-waves launch bound. LDS 26.6 KB.
// Measured: k_main 62.4us, VGPR 64, bank conflicts 164K, zero spill,
// absmax 1.95e-3 (threshold 1.04e-2).
// Full lever matrix (all regress vs this): 128-row tiles (r10/r12/r16),
// source-level load pipelining (r11), launch-bounds caps (r6/r12/r13:
// catastrophic spills), no-k-split (r17: VGPR 80 + 17x conflicts),
// setprio (r18: VGPR->76), dbuf fused staging (r20: VGPR->72).
// Any liveness-extending change crosses the 64-VGPR cliff and loses more
// occupancy than it gains — this structure is the measured local optimum.
// ---------------------------------------------------------------------------
__global__ __launch_bounds__(256) void k_main(
    const float* __restrict__ A, const float* __restrict__ Bm,
    const ushort* __restrict__ fb2, const ushort* __restrict__ fb3,
    const ushort* __restrict__ fb4,
    const float* __restrict__ b2, const float* __restrict__ b3,
    const float* __restrict__ b4, float* __restrict__ out) {
  __shared__ __align__(16) unsigned char smem[64 * SH + 64 * S3];  // 26624 B
  unsigned char* h1s = smem;             // [64][128 bf16] stride SH (per half)
  unsigned char* h2s = smem;             // [64][128 bf16] stride SH (alias)
  unsigned char* h3s = smem + 64 * SH;   // [64][ 64 bf16] stride S3 (disjoint)

  const int t = threadIdx.x;
  const int wid = t >> 6;        // 0..3
  const int l = t & 63;
  const int l31 = l & 31;
  const int l15 = l & 15;
  const int lh = l >> 5;         // 0..1
  const int wr = wid >> 1;       // 0..1 (32-row half)
  const int wc = wid & 1;        // 0..1 (col half)

  const bf16x8s* fb2v = (const bf16x8s*)fb2;
  const bf16x8s* fb3v = (const bf16x8s*)fb3;
  const bf16x8s* fb4v = (const bf16x8s*)fb4;

  const int rg0 = blockIdx.x * 64;
  const int q0 = rg0 / NROW;
  const int b0 = rg0 - q0 * NROW;
  const int ct0 = wc * 2;
  const unsigned char* abase2 = h1s + (32 * wr + l31) * SH;
  const int kh = lh * 16;   // byte offset of lane's 8-bf16 k-slice

  f32x16 acc2a, acc2b;
#pragma unroll
  for (int i = 0; i < 16; ++i) { acc2a[i] = 0.f; acc2b[i] = 0.f; }

  // ==== two k-halves: stage 64x128, then 8 MFMA k-steps ====
#pragma unroll
  for (int hf = 0; hf < 2; ++hf) {
    // ---- stage half hf: wave wid stages rows wid*16..+16
#pragma unroll
    for (int it = 0; it < 8; ++it) {
      const int row = wid * 16 + it * 2 + lh;
      int bb = b0 + row;
      int qq = q0;
      if (bb >= NROW) { bb -= NROW; qq += 1; }
      const int col = hf * 128 + l31 * 4;
      const float4 av = *(const float4*)(A + (size_t)qq * DN + col);
      const float4 bv = *(const float4*)(Bm + (size_t)bb * DN + col);
      ushort4 o;
      o.x = f2bf(fmaxf(av.x + bv.x, 0.f));
      o.y = f2bf(fmaxf(av.y + bv.y, 0.f));
      o.z = f2bf(fmaxf(av.z + bv.z, 0.f));
      o.w = f2bf(fmaxf(av.w + bv.w, 0.f));
      *(ushort4*)(h1s + row * SH + l31 * 8) = o;
    }
    __syncthreads();

    // ---- GEMM2 phase: 8 k-steps on this half (fb2 streamed)
#pragma unroll
    for (int ks = 0; ks < 8; ++ks) {
      const int ksg = hf * 8 + ks;
      const bf16x8s a = *(const bf16x8s*)(abase2 + ks * 32 + kh);
      const bf16x8s bA = fb2v[((ct0 + 0) * 16 + ksg) * 64 + l];
      const bf16x8s bB = fb2v[((ct0 + 1) * 16 + ksg) * 64 + l];
      acc2a = __builtin_amdgcn_mfma_f32_32x32x16_bf16(a, bA, acc2a, 0, 0, 0);
      acc2b = __builtin_amdgcn_mfma_f32_32x32x16_bf16(a, bB, acc2b, 0, 0, 0);
    }
    __syncthreads();   // half reads done before buffer reuse (stage/h2 alias)
  }

  // ---- h2 = relu(acc2 + b2) -> h2s (biases loaded HERE, not earlier)
  {
    const int c0g2 = 64 * wc + l31;
    const float bias2a = b2[c0g2];
    const float bias2b = b2[c0g2 + 32];
#pragma unroll
    for (int reg = 0; reg < 16; ++reg) {
      const int row = 32 * wr + (reg & 3) + 8 * (reg >> 2) + 4 * lh;
      *(ushort*)(h2s + row * SH + c0g2 * 2) =
          f2bf(fmaxf(acc2a[reg] + bias2a, 0.f));
      *(ushort*)(h2s + row * SH + c0g2 * 2 + 64) =
          f2bf(fmaxf(acc2b[reg] + bias2b, 0.f));
    }
  }
  __syncthreads();

  // ---- GEMM3: h3 = relu(h2 @ W3 + b3); fb3 streamed (L1-resident, 8 KB)
  f32x16 acc3;
#pragma unroll
  for (int i = 0; i < 16; ++i) acc3[i] = 0.f;
  {
    const unsigned char* abase = h2s + (32 * wr + l31) * SH;
#pragma unroll
    for (int ks = 0; ks < 8; ++ks) {
      const bf16x8s a = *(const bf16x8s*)(abase + ks * 32 + kh);
      const bf16x8s bb3 = fb3v[(wc * 8 + ks) * 64 + l];
      acc3 = __builtin_amdgcn_mfma_f32_32x32x16_bf16(a, bb3, acc3, 0, 0, 0);
    }
  }
  // h3s region is disjoint from h2s -> no barrier needed before writes
  {
    const float bias3 = b3[32 * wc + l31];   // loaded at use
#pragma unroll
    for (int reg = 0; reg < 16; ++reg) {
      const int row = 32 * wr + (reg & 3) + 8 * (reg >> 2) + 4 * lh;
      *(ushort*)(h3s + row * S3 + (32 * wc + l31) * 2) =
          f2bf(fmaxf(acc3[reg] + bias3, 0.f));
    }
  }
  __syncthreads();

  // ---- GEMM4 (16x16x32): wave wid owns rows 16*wid..+16 (one (q,c) group)
  // B4 fragments + bias loaded at use (L1-hit; keeps GEMM2/3 live set small)
  f32x4 acc4;
#pragma unroll
  for (int i = 0; i < 4; ++i) acc4[i] = 0.f;
  {
    const unsigned char* abase = h3s + (16 * wid + l15) * S3;
#pragma unroll
    for (int ks = 0; ks < 2; ++ks) {
      const bf16x8s a = *(const bf16x8s*)(abase + (l >> 4) * 16 + ks * 64);
      const bf16x8s b4f = fb4v[ks * 64 + l];
      acc4 = __builtin_amdgcn_mfma_f32_16x16x32_bf16(a, b4f, acc4, 0, 0, 0);
    }
  }

  // ---- epilogue: tanh, sum 10 cols, mean, sum 16 rows -> score
  {
    const float b4v = (l15 < H4N) ? b4[l15] : 0.f;
    float part = 0.f;
#pragma unroll
    for (int r = 0; r < 4; ++r) {
      const float v = fast_tanh(acc4[r] + b4v);
      part += (l15 < H4N) ? v : 0.f;
    }
    part += __shfl_xor(part, 1);
    part += __shfl_xor(part, 2);
    part += __shfl_xor(part, 4);
    part += __shfl_xor(part, 8);
    part += __shfl_xor(part, 16);
    part += __shfl_xor(part, 32);
    if (l == 0) out[(size_t)blockIdx.x * 4 + wid] = part * 0.1f;
  }
}

// ---------------------------------------------------------------------------
extern "C" void kernel_launch(void* const* d_in, const int* in_sizes, int n_in,
                              void* d_out, int out_size, void* d_ws, size_t ws_size,
                              hipStream_t stream) {
  const float* queries  = (const float*)d_in[0];
  const float* supports = (const float*)d_in[1];
  const float* W1 = (const float*)d_in[2];
  const float* b1 = (const float*)d_in[3];
  const float* W2 = (const float*)d_in[4];
  const float* b2 = (const float*)d_in[5];
  const float* W3 = (const float*)d_in[6];
  const float* b3 = (const float*)d_in[7];
  const float* W4 = (const float*)d_in[8];
  const float* b4 = (const float*)d_in[9];
  float* out = (float*)d_out;

  // workspace layout (fp32 A/Bm, then bf16 fragment buffers) ~2.35 MB
  float* A  = (float*)d_ws;                       // [2048][256]
  float* Bm = A + (size_t)QN * H1N;               // [160][256]
  ushort* fb2 = (ushort*)(Bm + (size_t)NROW * H1N);  // 64*512
  ushort* fb3 = fb2 + 64 * 512;                      // 16*512
  ushort* fb4 = fb3 + 16 * 512;                      // 2*512

  hipLaunchKernelGGL(k_pre, dim3(PRE_AB_BLOCKS + 21), dim3(256), 0, stream,
                     queries, supports, W1, b1, W2, W3, W4, A, Bm, fb2, fb3, fb4);
  hipLaunchKernelGGL(k_main, dim3((QN * CN * SN) / 64), dim3(256), 0, stream,
                     A, Bm, fb2, fb3, fb4, b2, b3, b4, out);
}